// Round 20
// baseline (250.099 us; speedup 1.0000x reference)
//
#include <hip/hip_runtime.h>
#include <math.h>

#define BB 8
#define LL 8192
#define DD 64
#define HH 128
#define NN 64
#define NLAYER 3
#define LC 64          // chunk length
#define NC 128         // chunks per (b,h) sequence
#define LST 137        // kG local-sums f16 row stride
#define SIS 136        // kG sinit f16 [c][n2] row stride

typedef _Float16 half_t;
typedef _Float16 f16x8_t __attribute__((ext_vector_type(8)));
typedef _Float16 f16x4_t __attribute__((ext_vector_type(4)));
typedef _Float16 f16x2_t __attribute__((ext_vector_type(2)));
typedef float    f32x4_t __attribute__((ext_vector_type(4)));

// workspace sizes in float units
#define SZ_WB   ((size_t)HH*NN*2)            // 16384 (per layer)
#define SZ_WGT  ((size_t)NLAYER*256*HH/2)    // 49152 (Wglu f16 [l][g][h])
#define SZ_WOT  ((size_t)DD*HH/2)            // 4096  (WoutT f16 [d][h])
#define SZ_WIT  ((size_t)HH*DD/2)            // 4096  (WinT f16 [h][d])
#define SZ_AM   ((size_t)HH*64*192/2)        // 786432  (f16, per layer)
#define SZ_HT   ((size_t)BB*HH*LL/2)         // 4194304 (f16 [b][h][l])
#define SZ_YT   ((size_t)BB*HH*LL/2)         // 4194304 (f16 [b][h][l])

// ---------------- kPrep: fused params + weight converts ----------------
__global__ __launch_bounds__(256) void kPrep(const float* __restrict__ logdt,
   const float* __restrict__ logA, const float* __restrict__ Aim,
   const float* __restrict__ Cre, const float* __restrict__ Cim,
   const float* __restrict__ Wglu, const float* __restrict__ Wout,
   const float* __restrict__ Win,
   float* __restrict__ wb3, float* __restrict__ wl3, half_t* __restrict__ Amat3,
   half_t* __restrict__ wgt, half_t* __restrict__ woT, half_t* __restrict__ wiT) {
  __shared__ float  ktap[4][64];
  __shared__ half_t gst[4][64][128];
  int bid = blockIdx.x;
  int t = threadIdx.x;
  if (bid < 96) {
    int layer = bid >> 5;
    int blk   = bid & 31;
    float* wb = wb3 + (size_t)layer*SZ_WB;
    float* wl = wl3 + (size_t)layer*SZ_WB;
    half_t* Amat = Amat3 + (size_t)layer*HH*64*192;
    int w = t >> 6;
    int n = t & 63;
    int h = blk*4 + w;
    float dt = expf(logdt[layer*HH + h]);
    int idx = (layer*HH + h)*NN + n;
    float ar = -expf(logA[idx]);
    float ai = Aim[idx];
    float er = expf(dt*ar);
    float wr = er*cosf(dt*ai), wi = er*sinf(dt*ai);   // w = exp(dt*A)
    float inv = 1.f/(ar*ar + ai*ai);
    float mr = wr - 1.f, mi = wi;                     // expm1(dtA)
    float tr = (mr*ar + mi*ai)*inv;                   // expm1(dtA)/A
    float ti = (mi*ar - mr*ai)*inv;
    float c0 = Cre[idx], c1 = Cim[idx];
    float cr = c0*tr - c1*ti, ci = c0*ti + c1*tr;     // C_eff
    wb[(h*NN+n)*2] = wr; wb[(h*NN+n)*2+1] = wi;
    float pr = 1.f, pi = 0.f;                         // w^d
    float qr = cr*wr - ci*wi, qi = cr*wi + ci*wr;     // C~ w^{d+1}
    for (int d = 0; d < 64; d++) {
      float kd = cr*pr - ci*pi;                       // Re(C~ w^d)
      kd += __shfl_xor(kd, 1);  kd += __shfl_xor(kd, 2);  kd += __shfl_xor(kd, 4);
      kd += __shfl_xor(kd, 8);  kd += __shfl_xor(kd, 16); kd += __shfl_xor(kd, 32);
      if (n == 0) ktap[w][d] = 2.f*kd;
      f16x2_t g2 = { (half_t)(2.f*qr), (half_t)(-2.f*qi) };
      *(f16x2_t*)&gst[w][d][2*n] = g2;
      float npr = pr*wr - pi*wi, npi = pr*wi + pi*wr; pr = npr; pi = npi;
      float nqr = qr*wr - qi*wi, nqi = qr*wi + qi*wr; qr = nqr; qi = nqi;
    }
    wl[(h*NN+n)*2] = pr; wl[(h*NN+n)*2+1] = pi;       // w^64
    __syncthreads();
    #pragma unroll
    for (int i = 0; i < 16; i++) {
      int idx2 = t + i*256;
      int hh = idx2 >> 10;
      int rem = idx2 & 1023;
      int l = rem >> 4, m8 = rem & 15;
      half_t* Ahh = Amat + (size_t)(blk*4 + hh)*64*192;
      *(f16x8_t*)&Ahh[(size_t)l*192 + 64 + m8*8] = *(const f16x8_t*)&gst[hh][l][m8*8];
    }
    #pragma unroll
    for (int i = 0; i < 8; i++) {
      int idx2 = t + i*256;
      int hh = idx2 >> 9;
      int rem = idx2 & 511;
      int l = rem >> 3, m8 = rem & 7;
      half_t* Ahh = Amat + (size_t)(blk*4 + hh)*64*192;
      f16x8_t v;
      #pragma unroll
      for (int j = 0; j < 8; j++) {
        int m = m8*8 + j;
        v[j] = (half_t)((m <= l) ? ktap[hh][l - m] : 0.f);
      }
      *(f16x8_t*)&Ahh[(size_t)l*192 + m8*8] = v;
    }
  } else if (bid < 144) {
    int tid = (bid - 96)*256 + t;        // < 12288
    const float* src = Wglu + (size_t)tid*8;
    f16x8_t v;
    #pragma unroll
    for (int i = 0; i < 8; i++) v[i] = (half_t)src[i];
    *(f16x8_t*)&wgt[(size_t)tid*8] = v;
  } else if (bid < 176) {
    int tid = (bid - 144)*256 + t;       // < 8192
    int d = tid >> 7, h = tid & 127;
    woT[d*HH + h] = (half_t)Wout[h*DD + d];
  } else {
    int tid = (bid - 176)*256 + t;       // < 8192
    int h = tid >> 6, d = tid & 63;
    wiT[h*DD + d] = (half_t)Win[d*HH + h];
  }
}

// ---------------- kIn: h = x @ W_in + b_in (MFMA) -> hT f16 [b][h][l] ----------------
__global__ __launch_bounds__(256) void kIn(const float* __restrict__ x,
      const half_t* __restrict__ wiT, const float* __restrict__ bin,
      half_t* __restrict__ hT) {
  __shared__ half_t xs[64*72];
  __shared__ half_t zs[128*72];
  size_t row0 = (size_t)blockIdx.x * 64;
  int t = threadIdx.x;
  #pragma unroll
  for (int i = 0; i < 4; i++) {
    int idx = t + i*256;
    int r = idx >> 4, c4 = idx & 15;
    float4 v = *(const float4*)&x[(row0 + r)*DD + c4*4];
    f16x4_t o = { (half_t)v.x, (half_t)v.y, (half_t)v.z, (half_t)v.w };
    *(f16x4_t*)&xs[r*72 + c4*4] = o;
  }
  __syncthreads();
  int wid = t >> 6, lane = t & 63;
  int lr = lane & 15, lq = lane >> 4, lk = lq*8;
  f32x4_t acc[4][2];
  #pragma unroll
  for (int mr = 0; mr < 4; mr++)
    #pragma unroll
    for (int nc = 0; nc < 2; nc++) {
      float bv = bin[(wid*2 + nc)*16 + lr];
      acc[mr][nc] = (f32x4_t){bv, bv, bv, bv};
    }
  #pragma unroll
  for (int ks = 0; ks < 2; ks++) {
    int k = ks*32 + lk;
    f16x8_t af[4], bf[2];
    #pragma unroll
    for (int mr = 0; mr < 4; mr++) af[mr] = *(const f16x8_t*)&xs[(mr*16 + lr)*72 + k];
    #pragma unroll
    for (int nc = 0; nc < 2; nc++)
      bf[nc] = *(const f16x8_t*)&wiT[(size_t)((wid*2 + nc)*16 + lr)*DD + k];
    #pragma unroll
    for (int mr = 0; mr < 4; mr++)
      #pragma unroll
      for (int nc = 0; nc < 2; nc++)
        acc[mr][nc] = __builtin_amdgcn_mfma_f32_16x16x32_f16(af[mr], bf[nc], acc[mr][nc], 0, 0, 0);
  }
  #pragma unroll
  for (int mr = 0; mr < 4; mr++)
    #pragma unroll
    for (int nc = 0; nc < 2; nc++) {
      int h = (wid*2 + nc)*16 + lr;
      f16x4_t v = { (half_t)acc[mr][nc][0], (half_t)acc[mr][nc][1],
                    (half_t)acc[mr][nc][2], (half_t)acc[mr][nc][3] };
      *(f16x4_t*)&zs[h*72 + mr*16 + lq*4] = v;
    }
  __syncthreads();
  size_t bb = row0 >> 13;
  int l0 = (int)(row0 & 8191);
  int h = t >> 1, hf = t & 1;
  half_t* dst = hT + ((size_t)bb*HH + h)*LL + l0 + hf*32;
  #pragma unroll
  for (int j = 0; j < 4; j++)
    *(f16x8_t*)&dst[j*8] = *(const f16x8_t*)&zs[h*72 + hf*32 + j*8];
}

// ---------------- kG: FUSED states GEMM + scan + output GEMM (512 thr, 76KB LDS) ----------------
__global__ __launch_bounds__(512) void kG(const half_t* __restrict__ hT,
      const float* __restrict__ wb, const float* __restrict__ wl,
      const half_t* __restrict__ Amat, half_t* __restrict__ yT) {
  __shared__ half_t va[128*72];          // V matrix; reused as y staging [c][72]
  __shared__ half_t ub[128*72];
  __shared__ half_t spad[128*LST];
  __shared__ float  segT[8*128];
  int t = threadIdx.x;
  int h = blockIdx.x >> 3, b = blockIdx.x & 7;
  {
    int n = t >> 3, q8 = t & 7;
    float wr = wb[(h*NN+n)*2], wi = wb[(h*NN+n)*2+1];
    float ar = wr, ai = wi;                      // -> w^8
    #pragma unroll
    for (int i = 0; i < 3; i++) { float nr = ar*ar - ai*ai, ni = 2.f*ar*ai; ar = nr; ai = ni; }
    float pr = 1.f, pi = 0.f;
    for (int e = 0; e < 7 - q8; e++) { float nr = pr*ar - pi*ai, ni = pr*ai + pi*ar; pr = nr; pi = ni; }
    int k0 = (7 - q8)*8;
    for (int i = 0; i < 8; i++) {
      int m = 63 - (k0 + i);
      va[(2*n)*72 + m]   = (half_t)pr;
      va[(2*n+1)*72 + m] = (half_t)pi;
      float nr = pr*wr - pi*wi, ni = pr*wi + pi*wr; pr = nr; pi = ni;
    }
  }
  {
    const half_t* src = hT + ((size_t)b*HH + h)*LL;
    #pragma unroll
    for (int i = 0; i < 2; i++) {
      int idx = t + i*512;
      int row = idx >> 3, off = (idx & 7)*8;
      *(f16x8_t*)&ub[row*72 + off] = *(const f16x8_t*)&src[row*64 + off];
    }
  }
  __syncthreads();
  int wid = t >> 6, lane = t & 63;
  int lr = lane & 15, lq = lane >> 4, lk = lq*8;
  {
    int wr_ = wid & 1, wc = wid >> 1;
    f32x4_t acc[4][2];
    #pragma unroll
    for (int mr = 0; mr < 4; mr++) { acc[mr][0] = (f32x4_t){0.f,0.f,0.f,0.f}; acc[mr][1] = (f32x4_t){0.f,0.f,0.f,0.f}; }
    #pragma unroll
    for (int ks = 0; ks < 2; ks++) {
      int k = ks*32 + lk;
      f16x8_t af[4], bf[2];
      #pragma unroll
      for (int mr = 0; mr < 4; mr++) af[mr] = *(const f16x8_t*)&va[(wr_*64 + mr*16 + lr)*72 + k];
      #pragma unroll
      for (int nc = 0; nc < 2; nc++) bf[nc] = *(const f16x8_t*)&ub[(wc*32 + nc*16 + lr)*72 + k];
      #pragma unroll
      for (int mr = 0; mr < 4; mr++)
        #pragma unroll
        for (int nc = 0; nc < 2; nc++)
          acc[mr][nc] = __builtin_amdgcn_mfma_f32_16x16x32_f16(af[mr], bf[nc], acc[mr][nc], 0, 0, 0);
    }
    #pragma unroll
    for (int mr = 0; mr < 4; mr++)
      #pragma unroll
      for (int nc = 0; nc < 2; nc++)
        #pragma unroll
        for (int r = 0; r < 4; r++)
          spad[(wr_*64 + mr*16 + lq*4 + r)*LST + (wc*32 + nc*16 + lr)] = (half_t)acc[mr][nc][r];
  }
  __syncthreads();
  {
    int n = t & 63, seg = t >> 6;
    int c0 = seg*16;
    float w64r = wl[(h*NN+n)*2], w64i = wl[(h*NN+n)*2+1];
    float pregr[16], pregi[16];
    float cr = 0.f, ci = 0.f;
    #pragma unroll
    for (int i = 0; i < 16; i++) {
      int c = c0 + i;
      float lre = (float)spad[(2*n)*LST + c];
      float lim = (float)spad[(2*n+1)*LST + c];
      pregr[i] = cr; pregi[i] = ci;
      float nr = fmaf(w64r, cr, fmaf(-w64i, ci, lre));
      float ni = fmaf(w64i, cr, fmaf(w64r, ci, lim));
      cr = nr; ci = ni;
    }
    segT[seg*128 + 2*n] = cr; segT[seg*128 + 2*n+1] = ci;
    __syncthreads();
    float ar = w64r, ai = w64i;           // -> w64^16
    #pragma unroll
    for (int i = 0; i < 4; i++) { float nr = ar*ar - ai*ai, ni = 2.f*ar*ai; ar = nr; ai = ni; }
    float br = 0.f, bi = 0.f;
    for (int k = 0; k < seg; k++) {
      float tr_ = segT[k*128 + 2*n], ti_ = segT[k*128 + 2*n+1];
      float nr = fmaf(ar, br, fmaf(-ai, bi, tr_));
      float ni = fmaf(ai, br, fmaf(ar, bi, ti_));
      br = nr; bi = ni;
    }
    float wpr = 1.f, wpi = 0.f;
    #pragma unroll
    for (int i = 0; i < 16; i++) {
      int c = c0 + i;
      float sr = pregr[i] + wpr*br - wpi*bi;
      float si = pregi[i] + wpr*bi + wpi*br;
      f16x2_t v = { (half_t)sr, (half_t)si };
      *(f16x2_t*)&spad[c*SIS + 2*n] = v;
      float nr = wpr*w64r - wpi*w64i, ni = wpr*w64i + wpi*w64r;
      wpr = nr; wpi = ni;
    }
  }
  __syncthreads();
  {
    const half_t* Ag = Amat + (size_t)h*64*192;
    f32x4_t acc[4];
    #pragma unroll
    for (int mr = 0; mr < 4; mr++) acc[mr] = (f32x4_t){0.f,0.f,0.f,0.f};
    int c = wid*16 + lr;
    #pragma unroll
    for (int ks = 0; ks < 6; ks++) {
      int k = ks*32 + lk;
      f16x8_t af[4];
      #pragma unroll
      for (int mr = 0; mr < 4; mr++) af[mr] = *(const f16x8_t*)&Ag[(size_t)(mr*16 + lr)*192 + k];
      f16x8_t bf = (ks < 2) ? *(const f16x8_t*)&ub[c*72 + k]
                            : *(const f16x8_t*)&spad[c*SIS + (k - 64)];
      #pragma unroll
      for (int mr = 0; mr < 4; mr++)
        acc[mr] = __builtin_amdgcn_mfma_f32_16x16x32_f16(af[mr], bf, acc[mr], 0, 0, 0);
    }
    #pragma unroll
    for (int mr = 0; mr < 4; mr++) {
      int l0 = mr*16 + lq*4;
      f16x4_t v = { (half_t)acc[mr][0], (half_t)acc[mr][1],
                    (half_t)acc[mr][2], (half_t)acc[mr][3] };
      *(f16x4_t*)&va[c*72 + l0] = v;
    }
  }
  __syncthreads();
  {
    half_t* yp = yT + ((size_t)b*HH + h)*LL;
    int c = t >> 2, q = t & 3;
    const half_t* src = &va[c*72 + q*16];
    f16x8_t v0 = *(const f16x8_t*)src;
    f16x8_t v1 = *(const f16x8_t*)(src + 8);
    *(f16x8_t*)&yp[c*64 + q*16]     = v0;
    *(f16x8_t*)&yp[c*64 + q*16 + 8] = v1;
  }
}

// ---------------- kD: 64-row blocks; ylds reused for z (af in regs across barrier);
// LDS 35.8KB for occupancy. gelu + MFMA GLU (+residual +fused norm partials) + scale.
// Last layer stages scaled z via ulds and fuses the out-GEMM.
__global__ __launch_bounds__(256) void kD(const half_t* __restrict__ yT,
     const half_t* __restrict__ hTin, const float* __restrict__ dskip,
     const half_t* __restrict__ wgt, const float* __restrict__ bglu,
     half_t* __restrict__ hT, const half_t* __restrict__ woT,
     const float* __restrict__ bout, float* __restrict__ out, int last) {
  __shared__ half_t ylds[64][136];     // gelu(y); later holds z
  __shared__ half_t ulds[64][136];     // residual u; later (last layer) scaled z
  __shared__ float  rpart[4][64];
  size_t row0 = (size_t)blockIdx.x * 64;
  int b  = (int)(row0 >> 13);
  int l0 = (int)(row0 & 8191);
  int t = threadIdx.x;
  int h  = t >> 1, hf = t & 1;
  int lbase = hf*32;
  const half_t* yb  = yT   + ((size_t)b*HH + h)*LL + l0 + lbase;
  const half_t* ubp = hTin + ((size_t)b*HH + h)*LL + l0 + lbase;
  float d = dskip[h];
  // ---- stage 1: 64B contiguous loads; gelu -> ylds; u -> ulds
  #pragma unroll
  for (int j = 0; j < 4; j++) {
    f16x8_t yv = *(const f16x8_t*)&yb[j*8];
    f16x8_t uv = *(const f16x8_t*)&ubp[j*8];
    #pragma unroll
    for (int i = 0; i < 8; i++) {
      float v = fmaf((float)uv[i], d, (float)yv[i]);
      float arg = 0.7978845608028654f*(v + 0.044715f*v*v*v);
      arg = fminf(fmaxf(arg, -15.f), 15.f);
      float e = __expf(2.f*arg);
      ylds[lbase + j*8 + i][h] = (half_t)(0.5f*v*(1.f + (e - 1.f)/(e + 1.f)));
      ulds[lbase + j*8 + i][h] = uv[i];
    }
  }
  __syncthreads();
  // ---- stage 2: af -> regs; barrier; MFMA; epilogue overwrites ylds with z
  {
    int w = t >> 6, lane = t & 63;
    int lr = lane & 15, lq = lane >> 4;
    f16x8_t af[4][4];
    #pragma unroll
    for (int mt = 0; mt < 4; mt++)
      #pragma unroll
      for (int ks = 0; ks < 4; ks++)
        af[mt][ks] = *(const f16x8_t*)&ylds[mt*16 + lr][ks*32 + lq*8];
    __syncthreads();                     // all ylds reads complete; safe to overwrite below
    int ntl[4] = { 2*w, 2*w+1, 2*w+8, 2*w+9 };
    f32x4_t acc[4][4];
    #pragma unroll
    for (int mt = 0; mt < 4; mt++)
      #pragma unroll
      for (int p = 0; p < 4; p++) acc[mt][p] = (f32x4_t){0.f,0.f,0.f,0.f};
    #pragma unroll
    for (int p = 0; p < 4; p++) {
      int nt = ntl[p];
      #pragma unroll
      for (int ks = 0; ks < 4; ks++) {
        f16x8_t bf = *(const f16x8_t*)&wgt[(size_t)(nt*16 + lr)*HH + ks*32 + lq*8];
        #pragma unroll
        for (int mt = 0; mt < 4; mt++)
          acc[mt][p] = __builtin_amdgcn_mfma_f32_16x16x32_f16(af[mt][ks], bf, acc[mt][p], 0, 0, 0);
      }
    }
    float sp[4][4];
    #pragma unroll
    for (int mt = 0; mt < 4; mt++)
      #pragma unroll
      for (int r = 0; r < 4; r++) sp[mt][r] = 0.f;
    #pragma unroll
    for (int p = 0; p < 2; p++) {
      int col = 32*w + p*16 + lr;
      float ba = bglu[col], bg = bglu[col + 128];
      #pragma unroll
      for (int mt = 0; mt < 4; mt++)
        #pragma unroll
        for (int r = 0; r < 4; r++) {
          int row = mt*16 + lq*4 + r;
          float a = acc[mt][p][r]   + ba;
          float g = acc[mt][p+2][r] + bg;
          float s = 1.f/(1.f + __expf(-g));
          float z = a*s + (float)ulds[row][col];
          ylds[row][col] = (half_t)z;
          sp[mt][r] = fmaf(z, z, sp[mt][r]);
        }
    }
    #pragma unroll
    for (int m = 1; m < 16; m <<= 1)
      #pragma unroll
      for (int mt = 0; mt < 4; mt++)
        #pragma unroll
        for (int r = 0; r < 4; r++) sp[mt][r] += __shfl_xor(sp[mt][r], m);
    if (lr == 0) {
      #pragma unroll
      for (int mt = 0; mt < 4; mt++)
        #pragma unroll
        for (int r = 0; r < 4; r++) rpart[w][mt*16 + lq*4 + r] = sp[mt][r];
    }
  }
  __syncthreads();
  // ---- stage 3: scale; 64B contiguous hT store / last-layer out-GEMM
  f16x8_t o[4];
  #pragma unroll
  for (int j = 0; j < 4; j++)
    #pragma unroll
    for (int i = 0; i < 8; i++) {
      int row = lbase + j*8 + i;
      float rn = rpart[0][row] + rpart[1][row] + rpart[2][row] + rpart[3][row];
      float sc = 11.313708498984761f / fmaxf(sqrtf(rn), 1e-12f);
      o[j][i] = (half_t)((float)ylds[row][h]*sc);
    }
  if (!last) {
    half_t* hb = hT + ((size_t)b*HH + h)*LL + l0 + lbase;
    #pragma unroll
    for (int j = 0; j < 4; j++) *(f16x8_t*)&hb[j*8] = o[j];
  } else {
    #pragma unroll
    for (int j = 0; j < 4; j++)
      #pragma unroll
      for (int i = 0; i < 8; i++) ulds[lbase + j*8 + i][h] = o[j][i];
    __syncthreads();
    int w = t >> 6, lane = t & 63;
    int lr = lane & 15, lq = lane >> 4;
    int dd = w*16 + lr;
    f32x4_t oacc[4];
    float bv = bout[dd];
    #pragma unroll
    for (int mt = 0; mt < 4; mt++) oacc[mt] = (f32x4_t){bv, bv, bv, bv};
    #pragma unroll
    for (int ks = 0; ks < 4; ks++) {
      int k = ks*32 + lq*8;
      f16x8_t bf = *(const f16x8_t*)&woT[(size_t)dd*HH + k];
      #pragma unroll
      for (int mt = 0; mt < 4; mt++) {
        f16x8_t af2 = *(const f16x8_t*)&ulds[mt*16 + lr][k];
        oacc[mt] = __builtin_amdgcn_mfma_f32_16x16x32_f16(af2, bf, oacc[mt], 0, 0, 0);
      }
    }
    #pragma unroll
    for (int mt = 0; mt < 4; mt++)
      #pragma unroll
      for (int r = 0; r < 4; r++)
        out[(row0 + mt*16 + lq*4 + r)*DD + dd] = oacc[mt][r];
  }
}

extern "C" void kernel_launch(void* const* d_in, const int* in_sizes, int n_in,
                              void* d_out, int out_size, void* d_ws, size_t ws_size,
                              hipStream_t stream) {
  const float* x     = (const float*)d_in[0];
  const float* Win   = (const float*)d_in[1];
  const float* bin   = (const float*)d_in[2];
  const float* logdt = (const float*)d_in[3];
  const float* logA  = (const float*)d_in[4];
  const float* Aim   = (const float*)d_in[5];
  const float* Cre   = (const float*)d_in[6];
  const float* Cim   = (const float*)d_in[7];
  const float* Dsk   = (const float*)d_in[8];
  const float* Wglu  = (const float*)d_in[9];
  const float* bglu  = (const float*)d_in[10];
  const float* Wout  = (const float*)d_in[11];
  const float* bout  = (const float*)d_in[12];
  float* out = (float*)d_out;

  // Total ≈ 43.6 MB (safe under the proven 104.2MB bound)
  float* ws   = (float*)d_ws;
  float* wb3  = ws;                          // 3*16384
  float* wl3  = wb3 + 3*SZ_WB;               // 3*16384
  float* wgtF = wl3 + 3*SZ_WB;               // 49152
  float* woTF = wgtF + SZ_WGT;               // 4096
  float* wiTF = woTF + SZ_WOT;               // 4096
  float* amF  = wiTF + SZ_WIT;               // Amat3 f16: 3*786432 (9.4MB)
  float* htF  = amF + 3*SZ_AM;               // hT f16 (16.8MB)
  float* ytF  = htF + SZ_HT;                 // yT f16 (16.8MB)
  half_t* wgt    = (half_t*)wgtF;
  half_t* woT    = (half_t*)woTF;
  half_t* wiT    = (half_t*)wiTF;
  half_t* Amat3  = (half_t*)amF;
  half_t* hT     = (half_t*)htF;
  half_t* yT     = (half_t*)ytF;

  kPrep<<<dim3(208), dim3(256), 0, stream>>>(logdt, logA, Aim, Cre, Cim,
                                             Wglu, Wout, Win,
                                             wb3, wl3, Amat3, wgt, woT, wiT);
  kIn<<<dim3(1024), dim3(256), 0, stream>>>(x, wiT, bin, hT);

  for (int layer = 0; layer < NLAYER; ++layer) {
    const float* wb = wb3 + (size_t)layer*SZ_WB;
    const float* wl = wl3 + (size_t)layer*SZ_WB;
    const half_t* Amat = Amat3 + (size_t)layer*HH*64*192;
    kG<<<dim3(1024), dim3(512), 0, stream>>>(hT, wb, wl, Amat, yT);
    kD<<<dim3(1024), dim3(256), 0, stream>>>(yT, hT, Dsk + layer*HH,
                       wgt + (size_t)layer*256*HH,
                       bglu + layer*2*HH, hT, woT, bout, out,
                       (layer == NLAYER-1) ? 1 : 0);
  }
}

// Round 21
// 225.517 us; speedup vs baseline: 1.1090x; 1.1090x over previous
//
#include <hip/hip_runtime.h>
#include <math.h>

#define BB 8
#define LL 8192
#define DD 64
#define HH 128
#define NN 64
#define NLAYER 3
#define LC 64          // chunk length
#define NC 128         // chunks per (b,h) sequence
#define LST 137        // kG local-sums f16 row stride
#define SIS 136        // kG sinit f16 [c][n2] row stride

typedef _Float16 half_t;
typedef _Float16 f16x8_t __attribute__((ext_vector_type(8)));
typedef _Float16 f16x4_t __attribute__((ext_vector_type(4)));
typedef _Float16 f16x2_t __attribute__((ext_vector_type(2)));
typedef float    f32x4_t __attribute__((ext_vector_type(4)));

// workspace sizes in float units
#define SZ_WB   ((size_t)HH*NN*2)            // 16384 (per layer)
#define SZ_WGT  ((size_t)NLAYER*256*HH/2)    // 49152 (Wglu f16 [l][g][h])
#define SZ_WOT  ((size_t)DD*HH/2)            // 4096  (WoutT f16 [d][h])
#define SZ_WIT  ((size_t)HH*DD/2)            // 4096  (WinT f16 [h][d])
#define SZ_AM   ((size_t)HH*64*192/2)        // 786432  (f16, per layer)
#define SZ_HT   ((size_t)BB*HH*LL/2)         // 4194304 (f16 [b][h][l])
#define SZ_YT   ((size_t)BB*HH*LL/2)         // 4194304 (f16 [b][h][l])

// ---------------- kPrep: fused params + weight converts ----------------
__global__ __launch_bounds__(256) void kPrep(const float* __restrict__ logdt,
   const float* __restrict__ logA, const float* __restrict__ Aim,
   const float* __restrict__ Cre, const float* __restrict__ Cim,
   const float* __restrict__ Wglu, const float* __restrict__ Wout,
   const float* __restrict__ Win,
   float* __restrict__ wb3, float* __restrict__ wl3, half_t* __restrict__ Amat3,
   half_t* __restrict__ wgt, half_t* __restrict__ woT, half_t* __restrict__ wiT) {
  __shared__ float  ktap[4][64];
  __shared__ half_t gst[4][64][128];
  int bid = blockIdx.x;
  int t = threadIdx.x;
  if (bid < 96) {
    int layer = bid >> 5;
    int blk   = bid & 31;
    float* wb = wb3 + (size_t)layer*SZ_WB;
    float* wl = wl3 + (size_t)layer*SZ_WB;
    half_t* Amat = Amat3 + (size_t)layer*HH*64*192;
    int w = t >> 6;
    int n = t & 63;
    int h = blk*4 + w;
    float dt = expf(logdt[layer*HH + h]);
    int idx = (layer*HH + h)*NN + n;
    float ar = -expf(logA[idx]);
    float ai = Aim[idx];
    float er = expf(dt*ar);
    float wr = er*cosf(dt*ai), wi = er*sinf(dt*ai);   // w = exp(dt*A)
    float inv = 1.f/(ar*ar + ai*ai);
    float mr = wr - 1.f, mi = wi;                     // expm1(dtA)
    float tr = (mr*ar + mi*ai)*inv;                   // expm1(dtA)/A
    float ti = (mi*ar - mr*ai)*inv;
    float c0 = Cre[idx], c1 = Cim[idx];
    float cr = c0*tr - c1*ti, ci = c0*ti + c1*tr;     // C_eff
    wb[(h*NN+n)*2] = wr; wb[(h*NN+n)*2+1] = wi;
    float pr = 1.f, pi = 0.f;                         // w^d
    float qr = cr*wr - ci*wi, qi = cr*wi + ci*wr;     // C~ w^{d+1}
    for (int d = 0; d < 64; d++) {
      float kd = cr*pr - ci*pi;                       // Re(C~ w^d)
      kd += __shfl_xor(kd, 1);  kd += __shfl_xor(kd, 2);  kd += __shfl_xor(kd, 4);
      kd += __shfl_xor(kd, 8);  kd += __shfl_xor(kd, 16); kd += __shfl_xor(kd, 32);
      if (n == 0) ktap[w][d] = 2.f*kd;
      f16x2_t g2 = { (half_t)(2.f*qr), (half_t)(-2.f*qi) };
      *(f16x2_t*)&gst[w][d][2*n] = g2;
      float npr = pr*wr - pi*wi, npi = pr*wi + pi*wr; pr = npr; pi = npi;
      float nqr = qr*wr - qi*wi, nqi = qr*wi + qi*wr; qr = nqr; qi = nqi;
    }
    wl[(h*NN+n)*2] = pr; wl[(h*NN+n)*2+1] = pi;       // w^64
    __syncthreads();
    #pragma unroll
    for (int i = 0; i < 16; i++) {
      int idx2 = t + i*256;
      int hh = idx2 >> 10;
      int rem = idx2 & 1023;
      int l = rem >> 4, m8 = rem & 15;
      half_t* Ahh = Amat + (size_t)(blk*4 + hh)*64*192;
      *(f16x8_t*)&Ahh[(size_t)l*192 + 64 + m8*8] = *(const f16x8_t*)&gst[hh][l][m8*8];
    }
    #pragma unroll
    for (int i = 0; i < 8; i++) {
      int idx2 = t + i*256;
      int hh = idx2 >> 9;
      int rem = idx2 & 511;
      int l = rem >> 3, m8 = rem & 7;
      half_t* Ahh = Amat + (size_t)(blk*4 + hh)*64*192;
      f16x8_t v;
      #pragma unroll
      for (int j = 0; j < 8; j++) {
        int m = m8*8 + j;
        v[j] = (half_t)((m <= l) ? ktap[hh][l - m] : 0.f);
      }
      *(f16x8_t*)&Ahh[(size_t)l*192 + m8*8] = v;
    }
  } else if (bid < 144) {
    int tid = (bid - 96)*256 + t;        // < 12288
    const float* src = Wglu + (size_t)tid*8;
    f16x8_t v;
    #pragma unroll
    for (int i = 0; i < 8; i++) v[i] = (half_t)src[i];
    *(f16x8_t*)&wgt[(size_t)tid*8] = v;
  } else if (bid < 176) {
    int tid = (bid - 144)*256 + t;       // < 8192
    int d = tid >> 7, h = tid & 127;
    woT[d*HH + h] = (half_t)Wout[h*DD + d];
  } else {
    int tid = (bid - 176)*256 + t;       // < 8192
    int h = tid >> 6, d = tid & 63;
    wiT[h*DD + d] = (half_t)Win[d*HH + h];
  }
}

// ---------------- kIn: h = x @ W_in + b_in (MFMA) -> hT f16 [b][h][l] ----------------
__global__ __launch_bounds__(256) void kIn(const float* __restrict__ x,
      const half_t* __restrict__ wiT, const float* __restrict__ bin,
      half_t* __restrict__ hT) {
  __shared__ half_t xs[64*72];
  __shared__ half_t zs[128*72];
  size_t row0 = (size_t)blockIdx.x * 64;
  int t = threadIdx.x;
  #pragma unroll
  for (int i = 0; i < 4; i++) {
    int idx = t + i*256;
    int r = idx >> 4, c4 = idx & 15;
    float4 v = *(const float4*)&x[(row0 + r)*DD + c4*4];
    f16x4_t o = { (half_t)v.x, (half_t)v.y, (half_t)v.z, (half_t)v.w };
    *(f16x4_t*)&xs[r*72 + c4*4] = o;
  }
  __syncthreads();
  int wid = t >> 6, lane = t & 63;
  int lr = lane & 15, lq = lane >> 4, lk = lq*8;
  f32x4_t acc[4][2];
  #pragma unroll
  for (int mr = 0; mr < 4; mr++)
    #pragma unroll
    for (int nc = 0; nc < 2; nc++) {
      float bv = bin[(wid*2 + nc)*16 + lr];
      acc[mr][nc] = (f32x4_t){bv, bv, bv, bv};
    }
  #pragma unroll
  for (int ks = 0; ks < 2; ks++) {
    int k = ks*32 + lk;
    f16x8_t af[4], bf[2];
    #pragma unroll
    for (int mr = 0; mr < 4; mr++) af[mr] = *(const f16x8_t*)&xs[(mr*16 + lr)*72 + k];
    #pragma unroll
    for (int nc = 0; nc < 2; nc++)
      bf[nc] = *(const f16x8_t*)&wiT[(size_t)((wid*2 + nc)*16 + lr)*DD + k];
    #pragma unroll
    for (int mr = 0; mr < 4; mr++)
      #pragma unroll
      for (int nc = 0; nc < 2; nc++)
        acc[mr][nc] = __builtin_amdgcn_mfma_f32_16x16x32_f16(af[mr], bf[nc], acc[mr][nc], 0, 0, 0);
  }
  #pragma unroll
  for (int mr = 0; mr < 4; mr++)
    #pragma unroll
    for (int nc = 0; nc < 2; nc++) {
      int h = (wid*2 + nc)*16 + lr;
      f16x4_t v = { (half_t)acc[mr][nc][0], (half_t)acc[mr][nc][1],
                    (half_t)acc[mr][nc][2], (half_t)acc[mr][nc][3] };
      *(f16x4_t*)&zs[h*72 + mr*16 + lq*4] = v;
    }
  __syncthreads();
  size_t bb = row0 >> 13;
  int l0 = (int)(row0 & 8191);
  int h = t >> 1, hf = t & 1;
  half_t* dst = hT + ((size_t)bb*HH + h)*LL + l0 + hf*32;
  #pragma unroll
  for (int j = 0; j < 4; j++)
    *(f16x8_t*)&dst[j*8] = *(const f16x8_t*)&zs[h*72 + hf*32 + j*8];
}

// ---------------- kG: FUSED states GEMM + scan + output GEMM (512 thr, 76KB LDS) ----------------
__global__ __launch_bounds__(512) void kG(const half_t* __restrict__ hT,
      const float* __restrict__ wb, const float* __restrict__ wl,
      const half_t* __restrict__ Amat, half_t* __restrict__ yT) {
  __shared__ half_t va[128*72];          // V matrix; reused as y staging [c][72]
  __shared__ half_t ub[128*72];
  __shared__ half_t spad[128*LST];
  __shared__ float  segT[8*128];
  int t = threadIdx.x;
  int h = blockIdx.x >> 3, b = blockIdx.x & 7;
  {
    int n = t >> 3, q8 = t & 7;
    float wr = wb[(h*NN+n)*2], wi = wb[(h*NN+n)*2+1];
    float ar = wr, ai = wi;                      // -> w^8
    #pragma unroll
    for (int i = 0; i < 3; i++) { float nr = ar*ar - ai*ai, ni = 2.f*ar*ai; ar = nr; ai = ni; }
    float pr = 1.f, pi = 0.f;
    for (int e = 0; e < 7 - q8; e++) { float nr = pr*ar - pi*ai, ni = pr*ai + pi*ar; pr = nr; pi = ni; }
    int k0 = (7 - q8)*8;
    for (int i = 0; i < 8; i++) {
      int m = 63 - (k0 + i);
      va[(2*n)*72 + m]   = (half_t)pr;
      va[(2*n+1)*72 + m] = (half_t)pi;
      float nr = pr*wr - pi*wi, ni = pr*wi + pi*wr; pr = nr; pi = ni;
    }
  }
  {
    const half_t* src = hT + ((size_t)b*HH + h)*LL;
    #pragma unroll
    for (int i = 0; i < 2; i++) {
      int idx = t + i*512;
      int row = idx >> 3, off = (idx & 7)*8;
      *(f16x8_t*)&ub[row*72 + off] = *(const f16x8_t*)&src[row*64 + off];
    }
  }
  __syncthreads();
  int wid = t >> 6, lane = t & 63;
  int lr = lane & 15, lq = lane >> 4, lk = lq*8;
  {
    int wr_ = wid & 1, wc = wid >> 1;
    f32x4_t acc[4][2];
    #pragma unroll
    for (int mr = 0; mr < 4; mr++) { acc[mr][0] = (f32x4_t){0.f,0.f,0.f,0.f}; acc[mr][1] = (f32x4_t){0.f,0.f,0.f,0.f}; }
    #pragma unroll
    for (int ks = 0; ks < 2; ks++) {
      int k = ks*32 + lk;
      f16x8_t af[4], bf[2];
      #pragma unroll
      for (int mr = 0; mr < 4; mr++) af[mr] = *(const f16x8_t*)&va[(wr_*64 + mr*16 + lr)*72 + k];
      #pragma unroll
      for (int nc = 0; nc < 2; nc++) bf[nc] = *(const f16x8_t*)&ub[(wc*32 + nc*16 + lr)*72 + k];
      #pragma unroll
      for (int mr = 0; mr < 4; mr++)
        #pragma unroll
        for (int nc = 0; nc < 2; nc++)
          acc[mr][nc] = __builtin_amdgcn_mfma_f32_16x16x32_f16(af[mr], bf[nc], acc[mr][nc], 0, 0, 0);
    }
    #pragma unroll
    for (int mr = 0; mr < 4; mr++)
      #pragma unroll
      for (int nc = 0; nc < 2; nc++)
        #pragma unroll
        for (int r = 0; r < 4; r++)
          spad[(wr_*64 + mr*16 + lq*4 + r)*LST + (wc*32 + nc*16 + lr)] = (half_t)acc[mr][nc][r];
  }
  __syncthreads();
  {
    int n = t & 63, seg = t >> 6;
    int c0 = seg*16;
    float w64r = wl[(h*NN+n)*2], w64i = wl[(h*NN+n)*2+1];
    float pregr[16], pregi[16];
    float cr = 0.f, ci = 0.f;
    #pragma unroll
    for (int i = 0; i < 16; i++) {
      int c = c0 + i;
      float lre = (float)spad[(2*n)*LST + c];
      float lim = (float)spad[(2*n+1)*LST + c];
      pregr[i] = cr; pregi[i] = ci;
      float nr = fmaf(w64r, cr, fmaf(-w64i, ci, lre));
      float ni = fmaf(w64i, cr, fmaf(w64r, ci, lim));
      cr = nr; ci = ni;
    }
    segT[seg*128 + 2*n] = cr; segT[seg*128 + 2*n+1] = ci;
    __syncthreads();
    float ar = w64r, ai = w64i;           // -> w64^16
    #pragma unroll
    for (int i = 0; i < 4; i++) { float nr = ar*ar - ai*ai, ni = 2.f*ar*ai; ar = nr; ai = ni; }
    float br = 0.f, bi = 0.f;
    for (int k = 0; k < seg; k++) {
      float tr_ = segT[k*128 + 2*n], ti_ = segT[k*128 + 2*n+1];
      float nr = fmaf(ar, br, fmaf(-ai, bi, tr_));
      float ni = fmaf(ai, br, fmaf(ar, bi, ti_));
      br = nr; bi = ni;
    }
    float wpr = 1.f, wpi = 0.f;
    #pragma unroll
    for (int i = 0; i < 16; i++) {
      int c = c0 + i;
      float sr = pregr[i] + wpr*br - wpi*bi;
      float si = pregi[i] + wpr*bi + wpi*br;
      f16x2_t v = { (half_t)sr, (half_t)si };
      *(f16x2_t*)&spad[c*SIS + 2*n] = v;
      float nr = wpr*w64r - wpi*w64i, ni = wpr*w64i + wpi*w64r;
      wpr = nr; wpi = ni;
    }
  }
  __syncthreads();
  {
    const half_t* Ag = Amat + (size_t)h*64*192;
    f32x4_t acc[4];
    #pragma unroll
    for (int mr = 0; mr < 4; mr++) acc[mr] = (f32x4_t){0.f,0.f,0.f,0.f};
    int c = wid*16 + lr;
    #pragma unroll
    for (int ks = 0; ks < 6; ks++) {
      int k = ks*32 + lk;
      f16x8_t af[4];
      #pragma unroll
      for (int mr = 0; mr < 4; mr++) af[mr] = *(const f16x8_t*)&Ag[(size_t)(mr*16 + lr)*192 + k];
      f16x8_t bf = (ks < 2) ? *(const f16x8_t*)&ub[c*72 + k]
                            : *(const f16x8_t*)&spad[c*SIS + (k - 64)];
      #pragma unroll
      for (int mr = 0; mr < 4; mr++)
        acc[mr] = __builtin_amdgcn_mfma_f32_16x16x32_f16(af[mr], bf, acc[mr], 0, 0, 0);
    }
    #pragma unroll
    for (int mr = 0; mr < 4; mr++) {
      int l0 = mr*16 + lq*4;
      f16x4_t v = { (half_t)acc[mr][0], (half_t)acc[mr][1],
                    (half_t)acc[mr][2], (half_t)acc[mr][3] };
      *(f16x4_t*)&va[c*72 + l0] = v;
    }
  }
  __syncthreads();
  {
    half_t* yp = yT + ((size_t)b*HH + h)*LL;
    int c = t >> 2, q = t & 3;
    const half_t* src = &va[c*72 + q*16];
    f16x8_t v0 = *(const f16x8_t*)src;
    f16x8_t v1 = *(const f16x8_t*)(src + 8);
    *(f16x8_t*)&yp[c*64 + q*16]     = v0;
    *(f16x8_t*)&yp[c*64 + q*16 + 8] = v1;
  }
}

// ---------------- kD: 64-row blocks; VALU diet: gelu = v*sigmoid(2x) via v_rcp;
// sigmoid via v_rcp; rmsnorm scale via v_rsq. Structure as round 20.
__global__ __launch_bounds__(256) void kD(const half_t* __restrict__ yT,
     const half_t* __restrict__ hTin, const float* __restrict__ dskip,
     const half_t* __restrict__ wgt, const float* __restrict__ bglu,
     half_t* __restrict__ hT, const half_t* __restrict__ woT,
     const float* __restrict__ bout, float* __restrict__ out, int last) {
  __shared__ half_t ylds[64][136];     // gelu(y); later holds z
  __shared__ half_t ulds[64][136];     // residual u; later (last layer) scaled z
  __shared__ float  rpart[4][64];
  size_t row0 = (size_t)blockIdx.x * 64;
  int b  = (int)(row0 >> 13);
  int l0 = (int)(row0 & 8191);
  int t = threadIdx.x;
  int h  = t >> 1, hf = t & 1;
  int lbase = hf*32;
  const half_t* yb  = yT   + ((size_t)b*HH + h)*LL + l0 + lbase;
  const half_t* ubp = hTin + ((size_t)b*HH + h)*LL + l0 + lbase;
  float d = dskip[h];
  // ---- stage 1: 64B contiguous loads; gelu = v*sigmoid(2*0.79788*(v+0.044715 v^3))
  #pragma unroll
  for (int j = 0; j < 4; j++) {
    f16x8_t yv = *(const f16x8_t*)&yb[j*8];
    f16x8_t uv = *(const f16x8_t*)&ubp[j*8];
    #pragma unroll
    for (int i = 0; i < 8; i++) {
      float v = fmaf((float)uv[i], d, (float)yv[i]);
      float arg2 = 1.5957691216057308f*(v + 0.044715f*v*v*v);
      arg2 = fminf(fmaxf(arg2, -30.f), 30.f);
      float e = __expf(-arg2);
      float o = v * __builtin_amdgcn_rcpf(1.f + e);
      ylds[lbase + j*8 + i][h] = (half_t)o;
      ulds[lbase + j*8 + i][h] = uv[i];
    }
  }
  __syncthreads();
  // ---- stage 2: af -> regs; barrier; MFMA; epilogue overwrites ylds with z
  {
    int w = t >> 6, lane = t & 63;
    int lr = lane & 15, lq = lane >> 4;
    f16x8_t af[4][4];
    #pragma unroll
    for (int mt = 0; mt < 4; mt++)
      #pragma unroll
      for (int ks = 0; ks < 4; ks++)
        af[mt][ks] = *(const f16x8_t*)&ylds[mt*16 + lr][ks*32 + lq*8];
    __syncthreads();                     // all ylds reads complete; safe to overwrite below
    int ntl[4] = { 2*w, 2*w+1, 2*w+8, 2*w+9 };
    f32x4_t acc[4][4];
    #pragma unroll
    for (int mt = 0; mt < 4; mt++)
      #pragma unroll
      for (int p = 0; p < 4; p++) acc[mt][p] = (f32x4_t){0.f,0.f,0.f,0.f};
    #pragma unroll
    for (int p = 0; p < 4; p++) {
      int nt = ntl[p];
      #pragma unroll
      for (int ks = 0; ks < 4; ks++) {
        f16x8_t bf = *(const f16x8_t*)&wgt[(size_t)(nt*16 + lr)*HH + ks*32 + lq*8];
        #pragma unroll
        for (int mt = 0; mt < 4; mt++)
          acc[mt][p] = __builtin_amdgcn_mfma_f32_16x16x32_f16(af[mt][ks], bf, acc[mt][p], 0, 0, 0);
      }
    }
    float sp[4][4];
    #pragma unroll
    for (int mt = 0; mt < 4; mt++)
      #pragma unroll
      for (int r = 0; r < 4; r++) sp[mt][r] = 0.f;
    #pragma unroll
    for (int p = 0; p < 2; p++) {
      int col = 32*w + p*16 + lr;
      float ba = bglu[col], bg = bglu[col + 128];
      #pragma unroll
      for (int mt = 0; mt < 4; mt++)
        #pragma unroll
        for (int r = 0; r < 4; r++) {
          int row = mt*16 + lq*4 + r;
          float a = acc[mt][p][r]   + ba;
          float g = acc[mt][p+2][r] + bg;
          float s = __builtin_amdgcn_rcpf(1.f + __expf(-g));
          float z = a*s + (float)ulds[row][col];
          ylds[row][col] = (half_t)z;
          sp[mt][r] = fmaf(z, z, sp[mt][r]);
        }
    }
    #pragma unroll
    for (int m = 1; m < 16; m <<= 1)
      #pragma unroll
      for (int mt = 0; mt < 4; mt++)
        #pragma unroll
        for (int r = 0; r < 4; r++) sp[mt][r] += __shfl_xor(sp[mt][r], m);
    if (lr == 0) {
      #pragma unroll
      for (int mt = 0; mt < 4; mt++)
        #pragma unroll
        for (int r = 0; r < 4; r++) rpart[w][mt*16 + lq*4 + r] = sp[mt][r];
    }
  }
  __syncthreads();
  // ---- stage 3: scale via v_rsq; 64B contiguous hT store / last-layer out-GEMM
  f16x8_t o[4];
  #pragma unroll
  for (int j = 0; j < 4; j++)
    #pragma unroll
    for (int i = 0; i < 8; i++) {
      int row = lbase + j*8 + i;
      float rn = rpart[0][row] + rpart[1][row] + rpart[2][row] + rpart[3][row];
      float sc = 11.313708498984761f * __builtin_amdgcn_rsqf(fmaxf(rn, 1e-24f));
      o[j][i] = (half_t)((float)ylds[row][h]*sc);
    }
  if (!last) {
    half_t* hb = hT + ((size_t)b*HH + h)*LL + l0 + lbase;
    #pragma unroll
    for (int j = 0; j < 4; j++) *(f16x8_t*)&hb[j*8] = o[j];
  } else {
    #pragma unroll
    for (int j = 0; j < 4; j++)
      #pragma unroll
      for (int i = 0; i < 8; i++) ulds[lbase + j*8 + i][h] = o[j][i];
    __syncthreads();
    int w = t >> 6, lane = t & 63;
    int lr = lane & 15, lq = lane >> 4;
    int dd = w*16 + lr;
    f32x4_t oacc[4];
    float bv = bout[dd];
    #pragma unroll
    for (int mt = 0; mt < 4; mt++) oacc[mt] = (f32x4_t){bv, bv, bv, bv};
    #pragma unroll
    for (int ks = 0; ks < 4; ks++) {
      int k = ks*32 + lq*8;
      f16x8_t bf = *(const f16x8_t*)&woT[(size_t)dd*HH + k];
      #pragma unroll
      for (int mt = 0; mt < 4; mt++) {
        f16x8_t af2 = *(const f16x8_t*)&ulds[mt*16 + lr][k];
        oacc[mt] = __builtin_amdgcn_mfma_f32_16x16x32_f16(af2, bf, oacc[mt], 0, 0, 0);
      }
    }
    #pragma unroll
    for (int mt = 0; mt < 4; mt++)
      #pragma unroll
      for (int r = 0; r < 4; r++)
        out[(row0 + mt*16 + lq*4 + r)*DD + dd] = oacc[mt][r];
  }
}

extern "C" void kernel_launch(void* const* d_in, const int* in_sizes, int n_in,
                              void* d_out, int out_size, void* d_ws, size_t ws_size,
                              hipStream_t stream) {
  const float* x     = (const float*)d_in[0];
  const float* Win   = (const float*)d_in[1];
  const float* bin   = (const float*)d_in[2];
  const float* logdt = (const float*)d_in[3];
  const float* logA  = (const float*)d_in[4];
  const float* Aim   = (const float*)d_in[5];
  const float* Cre   = (const float*)d_in[6];
  const float* Cim   = (const float*)d_in[7];
  const float* Dsk   = (const float*)d_in[8];
  const float* Wglu  = (const float*)d_in[9];
  const float* bglu  = (const float*)d_in[10];
  const float* Wout  = (const float*)d_in[11];
  const float* bout  = (const float*)d_in[12];
  float* out = (float*)d_out;

  // Total ≈ 43.6 MB (safe under the proven 104.2MB bound)
  float* ws   = (float*)d_ws;
  float* wb3  = ws;                          // 3*16384
  float* wl3  = wb3 + 3*SZ_WB;               // 3*16384
  float* wgtF = wl3 + 3*SZ_WB;               // 49152
  float* woTF = wgtF + SZ_WGT;               // 4096
  float* wiTF = woTF + SZ_WOT;               // 4096
  float* amF  = wiTF + SZ_WIT;               // Amat3 f16: 3*786432 (9.4MB)
  float* htF  = amF + 3*SZ_AM;               // hT f16 (16.8MB)
  float* ytF  = htF + SZ_HT;                 // yT f16 (16.8MB)
  half_t* wgt    = (half_t*)wgtF;
  half_t* woT    = (half_t*)woTF;
  half_t* wiT    = (half_t*)wiTF;
  half_t* Amat3  = (half_t*)amF;
  half_t* hT     = (half_t*)htF;
  half_t* yT     = (half_t*)ytF;

  kPrep<<<dim3(208), dim3(256), 0, stream>>>(logdt, logA, Aim, Cre, Cim,
                                             Wglu, Wout, Win,
                                             wb3, wl3, Amat3, wgt, woT, wiT);
  kIn<<<dim3(1024), dim3(256), 0, stream>>>(x, wiT, bin, hT);

  for (int layer = 0; layer < NLAYER; ++layer) {
    const float* wb = wb3 + (size_t)layer*SZ_WB;
    const float* wl = wl3 + (size_t)layer*SZ_WB;
    const half_t* Amat = Amat3 + (size_t)layer*HH*64*192;
    kG<<<dim3(1024), dim3(512), 0, stream>>>(hT, wb, wl, Amat, yT);
    kD<<<dim3(1024), dim3(256), 0, stream>>>(yT, hT, Dsk + layer*HH,
                       wgt + (size_t)layer*256*HH,
                       bglu + layer*2*HH, hT, woT, bout, out,
                       (layer == NLAYER-1) ? 1 : 0);
  }
}

// Round 22
// 222.754 us; speedup vs baseline: 1.1228x; 1.0124x over previous
//
#include <hip/hip_runtime.h>
#include <math.h>

#define BB 8
#define LL 8192
#define DD 64
#define HH 128
#define NN 64
#define NLAYER 3
#define LC 64          // chunk length
#define NC 128         // chunks per (b,h) sequence
#define LST 137        // kG local-sums f16 row stride
#define SIS 136        // kG sinit f16 [c][n2] row stride

typedef _Float16 half_t;
typedef _Float16 f16x8_t __attribute__((ext_vector_type(8)));
typedef _Float16 f16x4_t __attribute__((ext_vector_type(4)));
typedef _Float16 f16x2_t __attribute__((ext_vector_type(2)));
typedef float    f32x4_t __attribute__((ext_vector_type(4)));

// workspace sizes in float units
#define SZ_WB   ((size_t)HH*NN*2)            // 16384 (per layer)
#define SZ_WGT  ((size_t)NLAYER*256*HH/2)    // 49152 (Wglu f16 [l][g][h])
#define SZ_WOT  ((size_t)DD*HH/2)            // 4096  (WoutT f16 [d][h])
#define SZ_WIT  ((size_t)HH*DD/2)            // 4096  (WinT f16 [h][d])
#define SZ_AM   ((size_t)HH*64*192/2)        // 786432  (f16, per layer)
#define SZ_HT   ((size_t)BB*HH*LL/2)         // 4194304 (f16 [b][h][l])
#define SZ_YT   ((size_t)BB*HH*LL/2)         // 4194304 (f16 [b][h][l])

// ---------------- kPrep: fused params + weight converts ----------------
__global__ __launch_bounds__(256) void kPrep(const float* __restrict__ logdt,
   const float* __restrict__ logA, const float* __restrict__ Aim,
   const float* __restrict__ Cre, const float* __restrict__ Cim,
   const float* __restrict__ Wglu, const float* __restrict__ Wout,
   const float* __restrict__ Win,
   float* __restrict__ wb3, float* __restrict__ wl3, half_t* __restrict__ Amat3,
   half_t* __restrict__ wgt, half_t* __restrict__ woT, half_t* __restrict__ wiT) {
  __shared__ float  ktap[4][64];
  __shared__ half_t gst[4][64][128];
  int bid = blockIdx.x;
  int t = threadIdx.x;
  if (bid < 96) {
    int layer = bid >> 5;
    int blk   = bid & 31;
    float* wb = wb3 + (size_t)layer*SZ_WB;
    float* wl = wl3 + (size_t)layer*SZ_WB;
    half_t* Amat = Amat3 + (size_t)layer*HH*64*192;
    int w = t >> 6;
    int n = t & 63;
    int h = blk*4 + w;
    float dt = expf(logdt[layer*HH + h]);
    int idx = (layer*HH + h)*NN + n;
    float ar = -expf(logA[idx]);
    float ai = Aim[idx];
    float er = expf(dt*ar);
    float wr = er*cosf(dt*ai), wi = er*sinf(dt*ai);   // w = exp(dt*A)
    float inv = 1.f/(ar*ar + ai*ai);
    float mr = wr - 1.f, mi = wi;                     // expm1(dtA)
    float tr = (mr*ar + mi*ai)*inv;                   // expm1(dtA)/A
    float ti = (mi*ar - mr*ai)*inv;
    float c0 = Cre[idx], c1 = Cim[idx];
    float cr = c0*tr - c1*ti, ci = c0*ti + c1*tr;     // C_eff
    wb[(h*NN+n)*2] = wr; wb[(h*NN+n)*2+1] = wi;
    float pr = 1.f, pi = 0.f;                         // w^d
    float qr = cr*wr - ci*wi, qi = cr*wi + ci*wr;     // C~ w^{d+1}
    for (int d = 0; d < 64; d++) {
      float kd = cr*pr - ci*pi;                       // Re(C~ w^d)
      kd += __shfl_xor(kd, 1);  kd += __shfl_xor(kd, 2);  kd += __shfl_xor(kd, 4);
      kd += __shfl_xor(kd, 8);  kd += __shfl_xor(kd, 16); kd += __shfl_xor(kd, 32);
      if (n == 0) ktap[w][d] = 2.f*kd;
      f16x2_t g2 = { (half_t)(2.f*qr), (half_t)(-2.f*qi) };
      *(f16x2_t*)&gst[w][d][2*n] = g2;
      float npr = pr*wr - pi*wi, npi = pr*wi + pi*wr; pr = npr; pi = npi;
      float nqr = qr*wr - qi*wi, nqi = qr*wi + qi*wr; qr = nqr; qi = nqi;
    }
    wl[(h*NN+n)*2] = pr; wl[(h*NN+n)*2+1] = pi;       // w^64
    __syncthreads();
    #pragma unroll
    for (int i = 0; i < 16; i++) {
      int idx2 = t + i*256;
      int hh = idx2 >> 10;
      int rem = idx2 & 1023;
      int l = rem >> 4, m8 = rem & 15;
      half_t* Ahh = Amat + (size_t)(blk*4 + hh)*64*192;
      *(f16x8_t*)&Ahh[(size_t)l*192 + 64 + m8*8] = *(const f16x8_t*)&gst[hh][l][m8*8];
    }
    #pragma unroll
    for (int i = 0; i < 8; i++) {
      int idx2 = t + i*256;
      int hh = idx2 >> 9;
      int rem = idx2 & 511;
      int l = rem >> 3, m8 = rem & 7;
      half_t* Ahh = Amat + (size_t)(blk*4 + hh)*64*192;
      f16x8_t v;
      #pragma unroll
      for (int j = 0; j < 8; j++) {
        int m = m8*8 + j;
        v[j] = (half_t)((m <= l) ? ktap[hh][l - m] : 0.f);
      }
      *(f16x8_t*)&Ahh[(size_t)l*192 + m8*8] = v;
    }
  } else if (bid < 144) {
    int tid = (bid - 96)*256 + t;        // < 12288
    const float* src = Wglu + (size_t)tid*8;
    f16x8_t v;
    #pragma unroll
    for (int i = 0; i < 8; i++) v[i] = (half_t)src[i];
    *(f16x8_t*)&wgt[(size_t)tid*8] = v;
  } else if (bid < 176) {
    int tid = (bid - 144)*256 + t;       // < 8192
    int d = tid >> 7, h = tid & 127;
    woT[d*HH + h] = (half_t)Wout[h*DD + d];
  } else {
    int tid = (bid - 176)*256 + t;       // < 8192
    int h = tid >> 6, d = tid & 63;
    wiT[h*DD + d] = (half_t)Win[d*HH + h];
  }
}

// ---------------- kIn: h = x @ W_in + b_in (MFMA) -> hT f16 [b][h][l] ----------------
__global__ __launch_bounds__(256) void kIn(const float* __restrict__ x,
      const half_t* __restrict__ wiT, const float* __restrict__ bin,
      half_t* __restrict__ hT) {
  __shared__ half_t xs[64*72];
  __shared__ half_t zs[128*72];
  size_t row0 = (size_t)blockIdx.x * 64;
  int t = threadIdx.x;
  #pragma unroll
  for (int i = 0; i < 4; i++) {
    int idx = t + i*256;
    int r = idx >> 4, c4 = idx & 15;
    float4 v = *(const float4*)&x[(row0 + r)*DD + c4*4];
    f16x4_t o = { (half_t)v.x, (half_t)v.y, (half_t)v.z, (half_t)v.w };
    *(f16x4_t*)&xs[r*72 + c4*4] = o;
  }
  __syncthreads();
  int wid = t >> 6, lane = t & 63;
  int lr = lane & 15, lq = lane >> 4, lk = lq*8;
  f32x4_t acc[4][2];
  #pragma unroll
  for (int mr = 0; mr < 4; mr++)
    #pragma unroll
    for (int nc = 0; nc < 2; nc++) {
      float bv = bin[(wid*2 + nc)*16 + lr];
      acc[mr][nc] = (f32x4_t){bv, bv, bv, bv};
    }
  #pragma unroll
  for (int ks = 0; ks < 2; ks++) {
    int k = ks*32 + lk;
    f16x8_t af[4], bf[2];
    #pragma unroll
    for (int mr = 0; mr < 4; mr++) af[mr] = *(const f16x8_t*)&xs[(mr*16 + lr)*72 + k];
    #pragma unroll
    for (int nc = 0; nc < 2; nc++)
      bf[nc] = *(const f16x8_t*)&wiT[(size_t)((wid*2 + nc)*16 + lr)*DD + k];
    #pragma unroll
    for (int mr = 0; mr < 4; mr++)
      #pragma unroll
      for (int nc = 0; nc < 2; nc++)
        acc[mr][nc] = __builtin_amdgcn_mfma_f32_16x16x32_f16(af[mr], bf[nc], acc[mr][nc], 0, 0, 0);
  }
  #pragma unroll
  for (int mr = 0; mr < 4; mr++)
    #pragma unroll
    for (int nc = 0; nc < 2; nc++) {
      int h = (wid*2 + nc)*16 + lr;
      f16x4_t v = { (half_t)acc[mr][nc][0], (half_t)acc[mr][nc][1],
                    (half_t)acc[mr][nc][2], (half_t)acc[mr][nc][3] };
      *(f16x4_t*)&zs[h*72 + mr*16 + lq*4] = v;
    }
  __syncthreads();
  size_t bb = row0 >> 13;
  int l0 = (int)(row0 & 8191);
  int h = t >> 1, hf = t & 1;
  half_t* dst = hT + ((size_t)bb*HH + h)*LL + l0 + hf*32;
  #pragma unroll
  for (int j = 0; j < 4; j++)
    *(f16x8_t*)&dst[j*8] = *(const f16x8_t*)&zs[h*72 + hf*32 + j*8];
}

// ---------------- kG: FUSED states GEMM + scan + output GEMM (512 thr, 76KB LDS) ----------------
__global__ __launch_bounds__(512) void kG(const half_t* __restrict__ hT,
      const float* __restrict__ wb, const float* __restrict__ wl,
      const half_t* __restrict__ Amat, half_t* __restrict__ yT) {
  __shared__ half_t va[128*72];          // V matrix; reused as y staging [c][72]
  __shared__ half_t ub[128*72];
  __shared__ half_t spad[128*LST];
  __shared__ float  segT[8*128];
  int t = threadIdx.x;
  int h = blockIdx.x >> 3, b = blockIdx.x & 7;
  {
    int n = t >> 3, q8 = t & 7;
    float wr = wb[(h*NN+n)*2], wi = wb[(h*NN+n)*2+1];
    float ar = wr, ai = wi;                      // -> w^8
    #pragma unroll
    for (int i = 0; i < 3; i++) { float nr = ar*ar - ai*ai, ni = 2.f*ar*ai; ar = nr; ai = ni; }
    float pr = 1.f, pi = 0.f;
    for (int e = 0; e < 7 - q8; e++) { float nr = pr*ar - pi*ai, ni = pr*ai + pi*ar; pr = nr; pi = ni; }
    int k0 = (7 - q8)*8;
    for (int i = 0; i < 8; i++) {
      int m = 63 - (k0 + i);
      va[(2*n)*72 + m]   = (half_t)pr;
      va[(2*n+1)*72 + m] = (half_t)pi;
      float nr = pr*wr - pi*wi, ni = pr*wi + pi*wr; pr = nr; pi = ni;
    }
  }
  {
    const half_t* src = hT + ((size_t)b*HH + h)*LL;
    #pragma unroll
    for (int i = 0; i < 2; i++) {
      int idx = t + i*512;
      int row = idx >> 3, off = (idx & 7)*8;
      *(f16x8_t*)&ub[row*72 + off] = *(const f16x8_t*)&src[row*64 + off];
    }
  }
  __syncthreads();
  int wid = t >> 6, lane = t & 63;
  int lr = lane & 15, lq = lane >> 4, lk = lq*8;
  {
    int wr_ = wid & 1, wc = wid >> 1;
    f32x4_t acc[4][2];
    #pragma unroll
    for (int mr = 0; mr < 4; mr++) { acc[mr][0] = (f32x4_t){0.f,0.f,0.f,0.f}; acc[mr][1] = (f32x4_t){0.f,0.f,0.f,0.f}; }
    #pragma unroll
    for (int ks = 0; ks < 2; ks++) {
      int k = ks*32 + lk;
      f16x8_t af[4], bf[2];
      #pragma unroll
      for (int mr = 0; mr < 4; mr++) af[mr] = *(const f16x8_t*)&va[(wr_*64 + mr*16 + lr)*72 + k];
      #pragma unroll
      for (int nc = 0; nc < 2; nc++) bf[nc] = *(const f16x8_t*)&ub[(wc*32 + nc*16 + lr)*72 + k];
      #pragma unroll
      for (int mr = 0; mr < 4; mr++)
        #pragma unroll
        for (int nc = 0; nc < 2; nc++)
          acc[mr][nc] = __builtin_amdgcn_mfma_f32_16x16x32_f16(af[mr], bf[nc], acc[mr][nc], 0, 0, 0);
    }
    #pragma unroll
    for (int mr = 0; mr < 4; mr++)
      #pragma unroll
      for (int nc = 0; nc < 2; nc++)
        #pragma unroll
        for (int r = 0; r < 4; r++)
          spad[(wr_*64 + mr*16 + lq*4 + r)*LST + (wc*32 + nc*16 + lr)] = (half_t)acc[mr][nc][r];
  }
  __syncthreads();
  {
    int n = t & 63, seg = t >> 6;
    int c0 = seg*16;
    float w64r = wl[(h*NN+n)*2], w64i = wl[(h*NN+n)*2+1];
    float pregr[16], pregi[16];
    float cr = 0.f, ci = 0.f;
    #pragma unroll
    for (int i = 0; i < 16; i++) {
      int c = c0 + i;
      float lre = (float)spad[(2*n)*LST + c];
      float lim = (float)spad[(2*n+1)*LST + c];
      pregr[i] = cr; pregi[i] = ci;
      float nr = fmaf(w64r, cr, fmaf(-w64i, ci, lre));
      float ni = fmaf(w64i, cr, fmaf(w64r, ci, lim));
      cr = nr; ci = ni;
    }
    segT[seg*128 + 2*n] = cr; segT[seg*128 + 2*n+1] = ci;
    __syncthreads();
    float ar = w64r, ai = w64i;           // -> w64^16
    #pragma unroll
    for (int i = 0; i < 4; i++) { float nr = ar*ar - ai*ai, ni = 2.f*ar*ai; ar = nr; ai = ni; }
    float br = 0.f, bi = 0.f;
    for (int k = 0; k < seg; k++) {
      float tr_ = segT[k*128 + 2*n], ti_ = segT[k*128 + 2*n+1];
      float nr = fmaf(ar, br, fmaf(-ai, bi, tr_));
      float ni = fmaf(ai, br, fmaf(ar, bi, ti_));
      br = nr; bi = ni;
    }
    float wpr = 1.f, wpi = 0.f;
    #pragma unroll
    for (int i = 0; i < 16; i++) {
      int c = c0 + i;
      float sr = pregr[i] + wpr*br - wpi*bi;
      float si = pregi[i] + wpr*bi + wpi*br;
      f16x2_t v = { (half_t)sr, (half_t)si };
      *(f16x2_t*)&spad[c*SIS + 2*n] = v;
      float nr = wpr*w64r - wpi*w64i, ni = wpr*w64i + wpi*w64r;
      wpr = nr; wpi = ni;
    }
  }
  __syncthreads();
  {
    const half_t* Ag = Amat + (size_t)h*64*192;
    f32x4_t acc[4];
    #pragma unroll
    for (int mr = 0; mr < 4; mr++) acc[mr] = (f32x4_t){0.f,0.f,0.f,0.f};
    int c = wid*16 + lr;
    #pragma unroll
    for (int ks = 0; ks < 6; ks++) {
      int k = ks*32 + lk;
      f16x8_t af[4];
      #pragma unroll
      for (int mr = 0; mr < 4; mr++) af[mr] = *(const f16x8_t*)&Ag[(size_t)(mr*16 + lr)*192 + k];
      f16x8_t bf = (ks < 2) ? *(const f16x8_t*)&ub[c*72 + k]
                            : *(const f16x8_t*)&spad[c*SIS + (k - 64)];
      #pragma unroll
      for (int mr = 0; mr < 4; mr++)
        acc[mr] = __builtin_amdgcn_mfma_f32_16x16x32_f16(af[mr], bf, acc[mr], 0, 0, 0);
    }
    #pragma unroll
    for (int mr = 0; mr < 4; mr++) {
      int l0 = mr*16 + lq*4;
      f16x4_t v = { (half_t)acc[mr][0], (half_t)acc[mr][1],
                    (half_t)acc[mr][2], (half_t)acc[mr][3] };
      *(f16x4_t*)&va[c*72 + l0] = v;
    }
  }
  __syncthreads();
  {
    half_t* yp = yT + ((size_t)b*HH + h)*LL;
    int c = t >> 2, q = t & 3;
    const half_t* src = &va[c*72 + q*16];
    f16x8_t v0 = *(const f16x8_t*)src;
    f16x8_t v1 = *(const f16x8_t*)(src + 8);
    *(f16x8_t*)&yp[c*64 + q*16]     = v0;
    *(f16x8_t*)&yp[c*64 + q*16 + 8] = v1;
  }
}

// ---------------- kD: 512 threads, 64-row blocks; per-thread chain halved.
// 8 waves: wave w owns a-col tile w (cols 16w..16w+15) + gate tile w+8 (in-register pairing).
// gelu/sigmoid via rcp, scale via rsq. Last layer fuses out-GEMM.
__global__ __launch_bounds__(512) void kD(const half_t* __restrict__ yT,
     const half_t* __restrict__ hTin, const float* __restrict__ dskip,
     const half_t* __restrict__ wgt, const float* __restrict__ bglu,
     half_t* __restrict__ hT, const half_t* __restrict__ woT,
     const float* __restrict__ bout, float* __restrict__ out, int last) {
  __shared__ half_t ylds[64][136];     // gelu(y); later holds z
  __shared__ half_t ulds[64][136];     // residual u; later (last layer) scaled z
  __shared__ float  rpart[8][64];
  size_t row0 = (size_t)blockIdx.x * 64;
  int b  = (int)(row0 >> 13);
  int l0 = (int)(row0 & 8191);
  int t = threadIdx.x;
  int h = t >> 2, q = t & 3;
  int lbase = q*16;
  const half_t* yb  = yT   + ((size_t)b*HH + h)*LL + l0 + lbase;
  const half_t* ubp = hTin + ((size_t)b*HH + h)*LL + l0 + lbase;
  float d = dskip[h];
  // ---- stage 1: 16 elem/thread; 4-lane groups cover 128B contiguous per h
  #pragma unroll
  for (int j = 0; j < 2; j++) {
    f16x8_t yv = *(const f16x8_t*)&yb[j*8];
    f16x8_t uv = *(const f16x8_t*)&ubp[j*8];
    #pragma unroll
    for (int i = 0; i < 8; i++) {
      float v = fmaf((float)uv[i], d, (float)yv[i]);
      float arg2 = 1.5957691216057308f*(v + 0.044715f*v*v*v);
      arg2 = fminf(fmaxf(arg2, -30.f), 30.f);
      float e = __expf(-arg2);
      float o = v * __builtin_amdgcn_rcpf(1.f + e);
      ylds[lbase + j*8 + i][h] = (half_t)o;
      ulds[lbase + j*8 + i][h] = uv[i];
    }
  }
  __syncthreads();
  // ---- stage 2: MFMA GLU, 8 waves; epilogue 16 sigmoid/thread
  {
    int w = t >> 6, lane = t & 63;
    int lr = lane & 15, lq = lane >> 4;
    f32x4_t acc[4][2];
    #pragma unroll
    for (int mt = 0; mt < 4; mt++) { acc[mt][0] = (f32x4_t){0.f,0.f,0.f,0.f}; acc[mt][1] = (f32x4_t){0.f,0.f,0.f,0.f}; }
    #pragma unroll
    for (int ks = 0; ks < 4; ks++) {
      int k = ks*32 + lq*8;
      f16x8_t af[4];
      #pragma unroll
      for (int mt = 0; mt < 4; mt++) af[mt] = *(const f16x8_t*)&ylds[mt*16 + lr][k];
      f16x8_t bfa = *(const f16x8_t*)&wgt[(size_t)(w*16 + lr)*HH + k];
      f16x8_t bfg = *(const f16x8_t*)&wgt[(size_t)((w + 8)*16 + lr)*HH + k];
      #pragma unroll
      for (int mt = 0; mt < 4; mt++) {
        acc[mt][0] = __builtin_amdgcn_mfma_f32_16x16x32_f16(af[mt], bfa, acc[mt][0], 0, 0, 0);
        acc[mt][1] = __builtin_amdgcn_mfma_f32_16x16x32_f16(af[mt], bfg, acc[mt][1], 0, 0, 0);
      }
    }
    __syncthreads();                     // all ylds reads complete; safe to overwrite
    int col = w*16 + lr;
    float ba = bglu[col], bg = bglu[col + 128];
    float sp[4][4];
    #pragma unroll
    for (int mt = 0; mt < 4; mt++)
      #pragma unroll
      for (int r = 0; r < 4; r++) {
        int row = mt*16 + lq*4 + r;
        float a = acc[mt][0][r] + ba;
        float g = acc[mt][1][r] + bg;
        float s = __builtin_amdgcn_rcpf(1.f + __expf(-g));
        float z = a*s + (float)ulds[row][col];
        ylds[row][col] = (half_t)z;
        sp[mt][r] = z*z;
      }
    #pragma unroll
    for (int m = 1; m < 16; m <<= 1)
      #pragma unroll
      for (int mt = 0; mt < 4; mt++)
        #pragma unroll
        for (int r = 0; r < 4; r++) sp[mt][r] += __shfl_xor(sp[mt][r], m);
    if (lr == 0) {
      #pragma unroll
      for (int mt = 0; mt < 4; mt++)
        #pragma unroll
        for (int r = 0; r < 4; r++) rpart[w][mt*16 + lq*4 + r] = sp[mt][r];
    }
  }
  __syncthreads();
  // ---- stage 3: scale via rsq; 32B contiguous hT store / last-layer out-GEMM
  f16x8_t o0, o1;
  #pragma unroll
  for (int i = 0; i < 8; i++) {
    int row = lbase + i;
    float rn = rpart[0][row] + rpart[1][row] + rpart[2][row] + rpart[3][row]
             + rpart[4][row] + rpart[5][row] + rpart[6][row] + rpart[7][row];
    float sc = 11.313708498984761f * __builtin_amdgcn_rsqf(fmaxf(rn, 1e-24f));
    o0[i] = (half_t)((float)ylds[row][h]*sc);
  }
  #pragma unroll
  for (int i = 0; i < 8; i++) {
    int row = lbase + 8 + i;
    float rn = rpart[0][row] + rpart[1][row] + rpart[2][row] + rpart[3][row]
             + rpart[4][row] + rpart[5][row] + rpart[6][row] + rpart[7][row];
    float sc = 11.313708498984761f * __builtin_amdgcn_rsqf(fmaxf(rn, 1e-24f));
    o1[i] = (half_t)((float)ylds[row][h]*sc);
  }
  if (!last) {
    half_t* hb = hT + ((size_t)b*HH + h)*LL + l0 + lbase;
    *(f16x8_t*)hb = o0;
    *(f16x8_t*)(hb + 8) = o1;
  } else {
    #pragma unroll
    for (int i = 0; i < 8; i++) ulds[lbase + i][h]     = o0[i];
    #pragma unroll
    for (int i = 0; i < 8; i++) ulds[lbase + 8 + i][h] = o1[i];
    __syncthreads();
    int w = t >> 6, lane = t & 63;
    int lr = lane & 15, lq = lane >> 4;
    int dd = (w & 3)*16 + lr;            // 4 d-tiles
    int mth = (w >> 2)*2;                // 2 m-tile halves
    f32x4_t oacc[2];
    float bv = bout[dd];
    oacc[0] = (f32x4_t){bv, bv, bv, bv};
    oacc[1] = (f32x4_t){bv, bv, bv, bv};
    #pragma unroll
    for (int ks = 0; ks < 4; ks++) {
      int k = ks*32 + lq*8;
      f16x8_t bf = *(const f16x8_t*)&woT[(size_t)dd*HH + k];
      #pragma unroll
      for (int j = 0; j < 2; j++) {
        f16x8_t af2 = *(const f16x8_t*)&ulds[(mth + j)*16 + lr][k];
        oacc[j] = __builtin_amdgcn_mfma_f32_16x16x32_f16(af2, bf, oacc[j], 0, 0, 0);
      }
    }
    #pragma unroll
    for (int j = 0; j < 2; j++)
      #pragma unroll
      for (int r = 0; r < 4; r++)
        out[(row0 + (mth + j)*16 + lq*4 + r)*DD + dd] = oacc[j][r];
  }
}

extern "C" void kernel_launch(void* const* d_in, const int* in_sizes, int n_in,
                              void* d_out, int out_size, void* d_ws, size_t ws_size,
                              hipStream_t stream) {
  const float* x     = (const float*)d_in[0];
  const float* Win   = (const float*)d_in[1];
  const float* bin   = (const float*)d_in[2];
  const float* logdt = (const float*)d_in[3];
  const float* logA  = (const float*)d_in[4];
  const float* Aim   = (const float*)d_in[5];
  const float* Cre   = (const float*)d_in[6];
  const float* Cim   = (const float*)d_in[7];
  const float* Dsk   = (const float*)d_in[8];
  const float* Wglu  = (const float*)d_in[9];
  const float* bglu  = (const float*)d_in[10];
  const float* Wout  = (const float*)d_in[11];
  const float* bout  = (const float*)d_in[12];
  float* out = (float*)d_out;

  // Total ≈ 43.6 MB (safe under the proven 104.2MB bound)
  float* ws   = (float*)d_ws;
  float* wb3  = ws;                          // 3*16384
  float* wl3  = wb3 + 3*SZ_WB;               // 3*16384
  float* wgtF = wl3 + 3*SZ_WB;               // 49152
  float* woTF = wgtF + SZ_WGT;               // 4096
  float* wiTF = woTF + SZ_WOT;               // 4096
  float* amF  = wiTF + SZ_WIT;               // Amat3 f16: 3*786432 (9.4MB)
  float* htF  = amF + 3*SZ_AM;               // hT f16 (16.8MB)
  float* ytF  = htF + SZ_HT;                 // yT f16 (16.8MB)
  half_t* wgt    = (half_t*)wgtF;
  half_t* woT    = (half_t*)woTF;
  half_t* wiT    = (half_t*)wiTF;
  half_t* Amat3  = (half_t*)amF;
  half_t* hT     = (half_t*)htF;
  half_t* yT     = (half_t*)ytF;

  kPrep<<<dim3(208), dim3(256), 0, stream>>>(logdt, logA, Aim, Cre, Cim,
                                             Wglu, Wout, Win,
                                             wb3, wl3, Amat3, wgt, woT, wiT);
  kIn<<<dim3(1024), dim3(256), 0, stream>>>(x, wiT, bin, hT);

  for (int layer = 0; layer < NLAYER; ++layer) {
    const float* wb = wb3 + (size_t)layer*SZ_WB;
    const float* wl = wl3 + (size_t)layer*SZ_WB;
    const half_t* Amat = Amat3 + (size_t)layer*HH*64*192;
    kG<<<dim3(1024), dim3(512), 0, stream>>>(hT, wb, wl, Amat, yT);
    kD<<<dim3(1024), dim3(512), 0, stream>>>(yT, hT, Dsk + layer*HH,
                       wgt + (size_t)layer*256*HH,
                       bglu + layer*2*HH, hT, woT, bout, out,
                       (layer == NLAYER-1) ? 1 : 0);
  }
}